// Round 9
// baseline (111.850 us; speedup 1.0000x reference)
//
#include <hip/hip_runtime.h>

#define HW_ (1024 * 1024)

typedef _Float16 half8 __attribute__((ext_vector_type(8)));
typedef float f32x16 __attribute__((ext_vector_type(16)));
typedef unsigned int uint;

// R9: two v_mfma_f32_32x32x16_f16 per 32-pixel group (one image row).
//   D[32m][32n] = A[32m][16k] x B[16k][32n], chained over 2 instrs (K=32).
//   A (filters, M side): m = channel, INTERLEAVED: m=2j -> sel_j, m=2j+1 ->
//     green_j (j<8); m>=16 zero-pad. Lane m=lane&31, k=(lane>>5)*8+j.
//   B (image, N side): n = pixel (lane&31), k=(lane>>5)*8+j.
//   D: col=lane&31=pixel, row=(reg&3)+8*(reg>>2)+4*(lane>>5) [m74/m101] ->
//     regs 0..7 = 4 (sel,green) channel pairs per lane; regs 8..15 pad rows.
// Tap->k permutation (per row parity po) makes fragment reg-pairs dword-
// contiguous in LDS: pairs (pb+0,pb+1),(pb+2,pb+3) per window row, pb=po;
// singles at sdx=po?0:4. Gather per 32 px: 4x ds_read_b32 (instr0) +
// 1x b32 + 3x u16 (instr1) = 8 DS instrs (R8: 16 u16 per 32 px).
// Epilogue per 32 px: 4 exp2 + 4 fma in-register + 2 shfl_xor(32) (R8: 12
// shuffles). Pass-through value is a B-fragment tap on h=1 lanes -> free.
// R8 was DS-pipe-bound (~120 DS/wave ~= 41us); this is ~60 DS/wave.
__global__ __launch_bounds__(256, 2)
void demosaick_mfma2(const float* __restrict__ mosaick,
                     const float* __restrict__ sel_filts,
                     const float* __restrict__ green_filts,
                     float* __restrict__ out) {
    // smem element map (fp16):
    // [0,1360):      image tile 20 rows x 68 cols (64-wide tile, halo 2)
    // [1360,3408):   fA[po][m=32][kk=32]  (byte 2720, 16B aligned)
    // [3408,3440):   zero pad (dead-tap u16 reads)
    __shared__ __align__(16) _Float16 smem[3456];

    const int tid = threadIdx.x;
    const int b   = blockIdx.z;
    const int by0 = blockIdx.y * 16, bx0 = blockIdx.x * 64;
    const float* img = mosaick + (size_t)b * HW_;

    // ---- image staging: 20 x 68 fp16 ----
    for (int idx = tid; idx < 1360; idx += 256) {
        int row = idx / 68, col = idx - row * 68;
        int gy = by0 - 2 + row; gy = gy < 0 ? 0 : (gy > 1023 ? 1023 : gy);
        int gx = bx0 - 2 + col; gx = gx < 0 ? 0 : (gx > 1023 ? 1023 : gx);
        smem[idx] = (_Float16)img[gy * 1024 + gx];
    }
    // ---- filter staging with per-parity tap->k permutation ----
    for (int idx = tid; idx < 2048; idx += 256) {
        int po = idx >> 10, m = (idx >> 5) & 31, kk = idx & 31;
        int pb = po, sdx = po ? 0 : 4;
        int dy = -1, dx = 0;
        if (kk < 16)           { int h = kk >> 3, j = kk & 7;
                                 dy = 2 * h + (j >> 2); dx = pb + (j & 3); }
        else if (kk < 18)      { dy = 4; dx = pb + (kk - 16); }
        else if (kk == 18)     { dy = 0; dx = sdx; }
        else if (kk == 19)     { dy = 1; dx = sdx; }
        else if (kk == 20)     { dy = 2; dx = sdx; }
        else if (kk >= 24 && kk < 26) { dy = 4; dx = pb + 2 + (kk - 24); }
        else if (kk == 26)     { dy = 3; dx = sdx; }
        else if (kk == 27)     { dy = 4; dx = sdx; }
        float v = 0.f;
        if (m < 16 && dy >= 0)
            v = ((m & 1) ? green_filts : sel_filts)[(m >> 1) * 25 + dy * 5 + dx];
        smem[1360 + idx] = (_Float16)v;
    }
    for (int idx = tid; idx < 32; idx += 256) smem[3408 + idx] = (_Float16)0.f;
    __syncthreads();

    const int lane = tid & 63, w = tid >> 6;
    const int n = lane & 31, h = lane >> 5;   // n: channel(A) / pixel(B,D)

    // Hoisted A fragments: fA[po][m=n][kk], instr0 at kk=h*8, instr1 at 16+h*8
    const half8 a0p0 = *(const half8*)&smem[1360 +        n * 32 + h * 8];
    const half8 a1p0 = *(const half8*)&smem[1360 +        n * 32 + 16 + h * 8];
    const half8 a0p1 = *(const half8*)&smem[1360 + 1024 + n * 32 + h * 8];
    const half8 a1p1 = *(const half8*)&smem[1360 + 1024 + n * 32 + 16 + h * 8];

    const uint* smw = (const uint*)smem;
    const unsigned short* sms = (const unsigned short*)smem;
    float* outp = out + (size_t)b * HW_;
    const float L2E = 1.44269504f;

    #pragma unroll
    for (int u = 0; u < 4; ++u) {
        const int r  = 4 * w + u;            // tile row of computed pixels
        const int po = (u & 1) ^ 1;          // y=by0+r parity: even->po=1
        const int pb = po, sdx = po ? 0 : 4;
        // element addr: e(dy,dx) = (r+dy)*68 + 2n + po + dx
        const int e0 = (r + 2 * h) * 68 + 2 * n + po;   // rows 2h, 2h+1
        const int e4 = (r + 4) * 68 + 2 * n + po;
        const int rs0 = h ? 3 : 0, rs1 = h ? 4 : 1;

        uint B0x = smw[(e0 + pb) >> 1];
        uint B0y = smw[(e0 + pb + 2) >> 1];
        uint B0z = smw[(e0 + 68 + pb) >> 1];
        uint B0w = smw[(e0 + 68 + pb + 2) >> 1];
        uint B1x = smw[(e4 + pb + 2 * h) >> 1];
        uint us0 = sms[(r + rs0) * 68 + 2 * n + po + sdx];
        uint us1 = sms[(r + rs1) * 68 + 2 * n + po + sdx];
        uint B1y = us0 | (us1 << 16);
        uint B1z = sms[h ? 3408 : ((r + 2) * 68 + 2 * n + po + sdx)];
        uint B1w = 0;

        union { uint u4[4]; half8 v; } b0c = {{B0x, B0y, B0z, B0w}};
        union { uint u4[4]; half8 v; } b1c = {{B1x, B1y, B1z, B1w}};

        f32x16 acc = {};
        acc = __builtin_amdgcn_mfma_f32_32x32x16_f16(po ? a0p1 : a0p0, b0c.v, acc, 0, 0, 0);
        acc = __builtin_amdgcn_mfma_f32_32x32x16_f16(po ? a1p1 : a1p0, b1c.v, acc, 0, 0, 0);

        // regs 0..7: even=sel, odd=green (channel pairs)
        float se = 0.f, eg = 0.f;
        #pragma unroll
        for (int rr = 0; rr < 8; rr += 2) {
            float e = __builtin_amdgcn_exp2f(acc[rr] * L2E);
            se += e;
            eg = fmaf(e, acc[rr + 1], eg);
        }
        eg += __shfl_xor(eg, 32);
        se += __shfl_xor(se, 32);
        float gh = eg * __builtin_amdgcn_rcpf(se);

        if (h == 1) {
            // pass-through tap lives in this lane's B0 fragment:
            // po=1 -> (r2,d1)=b0[0]; po=0 -> (r2,d3)=b0[3]
            float pass = (float)(po ? b0c.v[0] : b0c.v[3]);
            float2 o;
            if (po) { o.x = pass; o.y = gh; }     // y even: (green@even, comp)
            else    { o.x = gh;   o.y = pass; }   // y odd:  (comp, green@odd)
            *(float2*)(outp + (size_t)(by0 + r) * 1024 + bx0 + 2 * n) = o;
        }
    }
}

extern "C" void kernel_launch(void* const* d_in, const int* in_sizes, int n_in,
                              void* d_out, int out_size, void* d_ws, size_t ws_size,
                              hipStream_t stream) {
    const float* mosaick     = (const float*)d_in[0];
    const float* sel_filts   = (const float*)d_in[1];
    const float* green_filts = (const float*)d_in[2];
    float* out = (float*)d_out;
    const int B = in_sizes[0] / HW_;          // 8
    dim3 grid(1024 / 64, 1024 / 16, B);       // (16, 64, 8) = 8192 blocks
    dim3 block(256, 1, 1);
    hipLaunchKernelGGL(demosaick_mfma2, grid, block, 0, stream,
                       mosaick, sel_filts, green_filts, out);
}

// Round 10
// 103.477 us; speedup vs baseline: 1.0809x; 1.0809x over previous
//
#include <hip/hip_runtime.h>

#define HW_ (1024 * 1024)

typedef _Float16 half8 __attribute__((ext_vector_type(8)));
typedef float f32x16 __attribute__((ext_vector_type(16)));
typedef unsigned int uint;

// ---------------------------------------------------------------------------
// R10. Structure = R9 (2x mfma_32x32x16_f16 per 32-px row-group, tap->k
// permutation making B-fragment reg-pairs dword-contiguous), with two fixes
// driven by R9 counters (VALU-issue-bound: filter-table rebuild ~250 VALU
// instrs/wave in EVERY block; plus 2 DS shuffles/group in the epilogue):
//  1) Filter table built ONCE into d_ws by a setup kernel; main kernel loads
//     A-fragments via 4x global dwordx4 (4KB table, L1-resident).
//  2) A rows 16..31 (previously zero) now DUPLICATE the 8 (sel,green) pairs
//     so each half-wave's D rows {(r&3)+8*(r>>2)+4h} cover all 16 channels:
//     row m -> pair p = 2*((m>>2)>>1)+((m&3)>>1), green iff (m&3)&1.
//     Every lane gets the full softmax input in-register -> NO shuffles.
//     h=1 lanes store (their B0 fragment contains the pass-through tap).
// ---------------------------------------------------------------------------

__device__ __forceinline__ void tap_from_kk(int po, int kk, int& dy, int& dx) {
    const int pb = po, sdx = po ? 0 : 4;
    dy = -1; dx = 0;
    if (kk < 16)           { int h = kk >> 3, j = kk & 7;
                             dy = 2 * h + (j >> 2); dx = pb + (j & 3); }
    else if (kk < 18)      { dy = 4; dx = pb + (kk - 16); }
    else if (kk == 18)     { dy = 0; dx = sdx; }
    else if (kk == 19)     { dy = 1; dx = sdx; }
    else if (kk == 20)     { dy = 2; dx = sdx; }
    else if (kk >= 24 && kk < 26) { dy = 4; dx = pb + 2 + (kk - 24); }
    else if (kk == 26)     { dy = 3; dx = sdx; }
    else if (kk == 27)     { dy = 4; dx = sdx; }
}

__global__ void build_filter_table(const float* __restrict__ sel_filts,
                                   const float* __restrict__ green_filts,
                                   _Float16* __restrict__ tbl) {
    int idx = blockIdx.x * 256 + threadIdx.x;     // 0..2047
    int po = idx >> 10, m = (idx >> 5) & 31, kk = idx & 31;
    int dy, dx;
    tap_from_kk(po, kk, dy, dx);
    float v = 0.f;
    if (dy >= 0) {
        int t = m & 3;
        int p = 2 * ((m >> 2) >> 1) + (t >> 1);   // pair 0..7 (dup over m>>3)
        v = ((t & 1) ? green_filts : sel_filts)[p * 25 + dy * 5 + dx];
    }
    tbl[idx] = (_Float16)v;
}

__global__ __launch_bounds__(256, 2)
void demosaick_main(const float* __restrict__ mosaick,
                    const _Float16* __restrict__ tbl,
                    float* __restrict__ out) {
    // [0,1360): image tile 20 rows x 68 cols fp16; [1360,1392): zero pad
    __shared__ __align__(16) _Float16 smem[1392];

    const int tid = threadIdx.x;
    const int b   = blockIdx.z;
    const int by0 = blockIdx.y * 16, bx0 = blockIdx.x * 64;
    const float* img = mosaick + (size_t)b * HW_;

    for (int idx = tid; idx < 1360; idx += 256) {
        int row = idx / 68, col = idx - row * 68;
        int gy = by0 - 2 + row; gy = gy < 0 ? 0 : (gy > 1023 ? 1023 : gy);
        int gx = bx0 - 2 + col; gx = gx < 0 ? 0 : (gx > 1023 ? 1023 : gx);
        smem[idx] = (_Float16)img[gy * 1024 + gx];
    }
    if (tid < 32) smem[1360 + tid] = (_Float16)0.f;
    __syncthreads();

    const int lane = tid & 63, w = tid >> 6;
    const int n = lane & 31, h = lane >> 5;       // n: A-row / pixel col

    // A fragments from the global table (L1-resident, 16B loads).
    const half8* t8 = (const half8*)tbl;
    const half8 a0p0 = t8[      n * 4 + h];       // po=0, kk=h*8
    const half8 a1p0 = t8[      n * 4 + 2 + h];   // po=0, kk=16+h*8
    const half8 a0p1 = t8[128 + n * 4 + h];       // po=1
    const half8 a1p1 = t8[128 + n * 4 + 2 + h];

    const uint* smw = (const uint*)smem;
    const unsigned short* sms = (const unsigned short*)smem;
    float* outp = out + (size_t)b * HW_;
    const float L2E = 1.44269504f;

    #pragma unroll
    for (int u = 0; u < 4; ++u) {
        const int r  = 4 * w + u;                 // tile row of computed px
        const int po = (u & 1) ^ 1;               // y=by0+r even -> po=1
        const int pb = po, sdx = po ? 0 : 4;
        const int e0 = (r + 2 * h) * 68 + 2 * n + po;
        const int e4 = (r + 4) * 68 + 2 * n + po;
        const int rs0 = h ? 3 : 0, rs1 = h ? 4 : 1;

        uint B0x = smw[(e0 + pb) >> 1];
        uint B0y = smw[(e0 + pb + 2) >> 1];
        uint B0z = smw[(e0 + 68 + pb) >> 1];
        uint B0w = smw[(e0 + 68 + pb + 2) >> 1];
        uint B1x = smw[(e4 + pb + 2 * h) >> 1];
        uint us0 = sms[(r + rs0) * 68 + 2 * n + po + sdx];
        uint us1 = sms[(r + rs1) * 68 + 2 * n + po + sdx];
        uint B1y = us0 | (us1 << 16);
        uint B1z = sms[h ? 1360 : ((r + 2) * 68 + 2 * n + po + sdx)];
        uint B1w = 0;

        union { uint u4[4]; half8 v; } b0c = {{B0x, B0y, B0z, B0w}};
        union { uint u4[4]; half8 v; } b1c = {{B1x, B1y, B1z, B1w}};

        f32x16 acc = {};
        acc = __builtin_amdgcn_mfma_f32_32x32x16_f16(po ? a0p1 : a0p0, b0c.v, acc, 0, 0, 0);
        acc = __builtin_amdgcn_mfma_f32_32x32x16_f16(po ? a1p1 : a1p0, b1c.v, acc, 0, 0, 0);

        // Channel-duplicated A: every lane holds all 8 (sel,green) pairs:
        // even regs = sel, odd regs = green. Softmax fully in-register.
        float se = 0.f, eg = 0.f;
        #pragma unroll
        for (int rr = 0; rr < 16; rr += 2) {
            float e = __builtin_amdgcn_exp2f(acc[rr] * L2E);
            se += e;
            eg = fmaf(e, acc[rr + 1], eg);
        }
        float gh = eg * __builtin_amdgcn_rcpf(se);

        if (h == 1) {
            // pass-through tap lives in this lane's B0 fragment (row r+2):
            // po=1 -> b0[0] (col 2n+2); po=0 -> b0[3] (col 2n+3)
            float pass = (float)(po ? b0c.v[0] : b0c.v[3]);
            float2 o;
            if (po) { o.x = pass; o.y = gh; }     // y even: (pass, comp)
            else    { o.x = gh;   o.y = pass; }   // y odd:  (comp, pass)
            *(float2*)(outp + (size_t)(by0 + r) * 1024 + bx0 + 2 * n) = o;
        }
    }
}

// ---- fallback (ws too small): self-contained R9 kernel, verified 47 us ----
__global__ __launch_bounds__(256, 2)
void demosaick_fallback(const float* __restrict__ mosaick,
                        const float* __restrict__ sel_filts,
                        const float* __restrict__ green_filts,
                        float* __restrict__ out) {
    __shared__ __align__(16) _Float16 smem[3456];
    const int tid = threadIdx.x;
    const int b   = blockIdx.z;
    const int by0 = blockIdx.y * 16, bx0 = blockIdx.x * 64;
    const float* img = mosaick + (size_t)b * HW_;

    for (int idx = tid; idx < 1360; idx += 256) {
        int row = idx / 68, col = idx - row * 68;
        int gy = by0 - 2 + row; gy = gy < 0 ? 0 : (gy > 1023 ? 1023 : gy);
        int gx = bx0 - 2 + col; gx = gx < 0 ? 0 : (gx > 1023 ? 1023 : gx);
        smem[idx] = (_Float16)img[gy * 1024 + gx];
    }
    for (int idx = tid; idx < 2048; idx += 256) {
        int po = idx >> 10, m = (idx >> 5) & 31, kk = idx & 31;
        int dy, dx;
        tap_from_kk(po, kk, dy, dx);
        float v = 0.f;
        if (dy >= 0) {
            int t = m & 3;
            int p = 2 * ((m >> 2) >> 1) + (t >> 1);
            v = ((t & 1) ? green_filts : sel_filts)[p * 25 + dy * 5 + dx];
        }
        smem[1360 + idx] = (_Float16)v;
    }
    for (int idx = tid; idx < 32; idx += 256) smem[3408 + idx] = (_Float16)0.f;
    __syncthreads();

    const int lane = tid & 63, w = tid >> 6;
    const int n = lane & 31, h = lane >> 5;
    const half8 a0p0 = *(const half8*)&smem[1360 +        n * 32 + h * 8];
    const half8 a1p0 = *(const half8*)&smem[1360 +        n * 32 + 16 + h * 8];
    const half8 a0p1 = *(const half8*)&smem[1360 + 1024 + n * 32 + h * 8];
    const half8 a1p1 = *(const half8*)&smem[1360 + 1024 + n * 32 + 16 + h * 8];

    const uint* smw = (const uint*)smem;
    const unsigned short* sms = (const unsigned short*)smem;
    float* outp = out + (size_t)b * HW_;
    const float L2E = 1.44269504f;

    #pragma unroll
    for (int u = 0; u < 4; ++u) {
        const int r  = 4 * w + u;
        const int po = (u & 1) ^ 1;
        const int pb = po, sdx = po ? 0 : 4;
        const int e0 = (r + 2 * h) * 68 + 2 * n + po;
        const int e4 = (r + 4) * 68 + 2 * n + po;
        const int rs0 = h ? 3 : 0, rs1 = h ? 4 : 1;

        uint B0x = smw[(e0 + pb) >> 1];
        uint B0y = smw[(e0 + pb + 2) >> 1];
        uint B0z = smw[(e0 + 68 + pb) >> 1];
        uint B0w = smw[(e0 + 68 + pb + 2) >> 1];
        uint B1x = smw[(e4 + pb + 2 * h) >> 1];
        uint us0 = sms[(r + rs0) * 68 + 2 * n + po + sdx];
        uint us1 = sms[(r + rs1) * 68 + 2 * n + po + sdx];
        uint B1y = us0 | (us1 << 16);
        uint B1z = sms[h ? 3408 : ((r + 2) * 68 + 2 * n + po + sdx)];
        uint B1w = 0;

        union { uint u4[4]; half8 v; } b0c = {{B0x, B0y, B0z, B0w}};
        union { uint u4[4]; half8 v; } b1c = {{B1x, B1y, B1z, B1w}};

        f32x16 acc = {};
        acc = __builtin_amdgcn_mfma_f32_32x32x16_f16(po ? a0p1 : a0p0, b0c.v, acc, 0, 0, 0);
        acc = __builtin_amdgcn_mfma_f32_32x32x16_f16(po ? a1p1 : a1p0, b1c.v, acc, 0, 0, 0);

        float se = 0.f, eg = 0.f;
        #pragma unroll
        for (int rr = 0; rr < 16; rr += 2) {
            float e = __builtin_amdgcn_exp2f(acc[rr] * L2E);
            se += e;
            eg = fmaf(e, acc[rr + 1], eg);
        }
        float gh = eg * __builtin_amdgcn_rcpf(se);

        if (h == 1) {
            float pass = (float)(po ? b0c.v[0] : b0c.v[3]);
            float2 o;
            if (po) { o.x = pass; o.y = gh; }
            else    { o.x = gh;   o.y = pass; }
            *(float2*)(outp + (size_t)(by0 + r) * 1024 + bx0 + 2 * n) = o;
        }
    }
}

extern "C" void kernel_launch(void* const* d_in, const int* in_sizes, int n_in,
                              void* d_out, int out_size, void* d_ws, size_t ws_size,
                              hipStream_t stream) {
    const float* mosaick     = (const float*)d_in[0];
    const float* sel_filts   = (const float*)d_in[1];
    const float* green_filts = (const float*)d_in[2];
    float* out = (float*)d_out;
    const int B = in_sizes[0] / HW_;          // 8
    dim3 grid(1024 / 64, 1024 / 16, B);       // (16, 64, 8) = 8192 blocks
    dim3 block(256, 1, 1);

    if (ws_size >= 4096) {
        _Float16* tbl = (_Float16*)d_ws;
        hipLaunchKernelGGL(build_filter_table, dim3(8), dim3(256), 0, stream,
                           sel_filts, green_filts, tbl);
        hipLaunchKernelGGL(demosaick_main, grid, block, 0, stream,
                           mosaick, tbl, out);
    } else {
        hipLaunchKernelGGL(demosaick_fallback, grid, block, 0, stream,
                           mosaick, sel_filts, green_filts, out);
    }
}

// Round 11
// 101.463 us; speedup vs baseline: 1.1024x; 1.0198x over previous
//
#include <hip/hip_runtime.h>

#define HW_ (1024 * 1024)

typedef _Float16 half8 __attribute__((ext_vector_type(8)));
typedef __fp16 fp16x2 __attribute__((ext_vector_type(2)));
typedef float f32x16 __attribute__((ext_vector_type(16)));
typedef unsigned int uint;

// ---------------------------------------------------------------------------
// R11 = R10 (2x mfma_32x32x16_f16 / 32-px row-group, precomputed filter table
// in d_ws, channel-duplicated A -> shuffle-free softmax) + latency fixes:
//  1) ALL four groups' B-fragment LDS gathers hoisted ahead of the MFMAs.
//     R10's VGPR=32 showed the compiler serialized group-by-group:
//     ds_read(120cy) -> MFMA -> exp2 chain, repeated 4x = latency-bound.
//     32 independent ds_reads in flight breaks that chain (VGPR ~90 OK;
//     R2 lesson: stay under 128 / launch_bounds(256,2)).
//  2) Interior-block staging vectorized: float2 global load + cvt_pkrtz ->
//     single dword LDS store; dword index == loop index (layout identity).
// ---------------------------------------------------------------------------

__device__ __forceinline__ void tap_from_kk(int po, int kk, int& dy, int& dx) {
    const int pb = po, sdx = po ? 0 : 4;
    dy = -1; dx = 0;
    if (kk < 16)           { int h = kk >> 3, j = kk & 7;
                             dy = 2 * h + (j >> 2); dx = pb + (j & 3); }
    else if (kk < 18)      { dy = 4; dx = pb + (kk - 16); }
    else if (kk == 18)     { dy = 0; dx = sdx; }
    else if (kk == 19)     { dy = 1; dx = sdx; }
    else if (kk == 20)     { dy = 2; dx = sdx; }
    else if (kk >= 24 && kk < 26) { dy = 4; dx = pb + 2 + (kk - 24); }
    else if (kk == 26)     { dy = 3; dx = sdx; }
    else if (kk == 27)     { dy = 4; dx = sdx; }
}

__global__ void build_filter_table(const float* __restrict__ sel_filts,
                                   const float* __restrict__ green_filts,
                                   _Float16* __restrict__ tbl) {
    int idx = blockIdx.x * 256 + threadIdx.x;     // 0..2047
    int po = idx >> 10, m = (idx >> 5) & 31, kk = idx & 31;
    int dy, dx;
    tap_from_kk(po, kk, dy, dx);
    float v = 0.f;
    if (dy >= 0) {
        int t = m & 3;
        int p = 2 * ((m >> 2) >> 1) + (t >> 1);   // pair 0..7 (dup over m>>3)
        v = ((t & 1) ? green_filts : sel_filts)[p * 25 + dy * 5 + dx];
    }
    tbl[idx] = (_Float16)v;
}

__global__ __launch_bounds__(256, 2)
void demosaick_main(const float* __restrict__ mosaick,
                    const _Float16* __restrict__ tbl,
                    float* __restrict__ out) {
    // [0,1360): image tile 20 rows x 68 cols fp16; [1360,1392): zero pad
    __shared__ __align__(16) _Float16 smem[1392];

    const int tid = threadIdx.x;
    const int b   = blockIdx.z;
    const int by0 = blockIdx.y * 16, bx0 = blockIdx.x * 64;
    const float* img = mosaick + (size_t)b * HW_;

    const bool interior = (blockIdx.x != 0) & (blockIdx.x != gridDim.x - 1) &
                          (blockIdx.y != 0) & (blockIdx.y != gridDim.y - 1);
    if (interior) {
        // 680 dwords; dword index == idx; rows of 34 float2.
        uint* smw_w = (uint*)smem;
        for (int idx = tid; idx < 680; idx += 256) {
            int row = idx / 34, c2 = idx - row * 34;
            float2 v = *(const float2*)(img + (size_t)(by0 - 2 + row) * 1024
                                            + (bx0 - 2 + 2 * c2));
            union { fp16x2 h; uint u; } cv;
            cv.h = __builtin_amdgcn_cvt_pkrtz(v.x, v.y);
            smw_w[idx] = cv.u;
        }
    } else {
        for (int idx = tid; idx < 1360; idx += 256) {
            int row = idx / 68, col = idx - row * 68;
            int gy = by0 - 2 + row; gy = gy < 0 ? 0 : (gy > 1023 ? 1023 : gy);
            int gx = bx0 - 2 + col; gx = gx < 0 ? 0 : (gx > 1023 ? 1023 : gx);
            smem[idx] = (_Float16)img[gy * 1024 + gx];
        }
    }
    if (tid < 32) smem[1360 + tid] = (_Float16)0.f;
    __syncthreads();

    const int lane = tid & 63, w = tid >> 6;
    const int n = lane & 31, h = lane >> 5;       // n: A-row / pixel col

    // A fragments from the global table (L1-resident, 16B loads).
    const half8* t8 = (const half8*)tbl;
    const half8 a0p0 = t8[      n * 4 + h];       // po=0, kk=h*8
    const half8 a1p0 = t8[      n * 4 + 2 + h];   // po=0, kk=16+h*8
    const half8 a0p1 = t8[128 + n * 4 + h];       // po=1
    const half8 a1p1 = t8[128 + n * 4 + 2 + h];

    const uint* smw = (const uint*)smem;
    const unsigned short* sms = (const unsigned short*)smem;
    float* outp = out + (size_t)b * HW_;
    const float L2E = 1.44269504f;

    // ---- Stage 1: ALL B-fragment gathers (independent, overlap latency) ----
    uint B0[4][4], B1[4][4];
    #pragma unroll
    for (int u = 0; u < 4; ++u) {
        const int r  = 4 * w + u;                 // tile row of computed px
        const int po = (u & 1) ^ 1;               // y=by0+r even -> po=1
        const int pb = po, sdx = po ? 0 : 4;
        const int e0 = (r + 2 * h) * 68 + 2 * n + po;
        const int e4 = (r + 4) * 68 + 2 * n + po;
        const int rs0 = h ? 3 : 0, rs1 = h ? 4 : 1;

        B0[u][0] = smw[(e0 + pb) >> 1];
        B0[u][1] = smw[(e0 + pb + 2) >> 1];
        B0[u][2] = smw[(e0 + 68 + pb) >> 1];
        B0[u][3] = smw[(e0 + 68 + pb + 2) >> 1];
        B1[u][0] = smw[(e4 + pb + 2 * h) >> 1];
        uint us0 = sms[(r + rs0) * 68 + 2 * n + po + sdx];
        uint us1 = sms[(r + rs1) * 68 + 2 * n + po + sdx];
        B1[u][1] = us0 | (us1 << 16);
        B1[u][2] = sms[h ? 1360 : ((r + 2) * 68 + 2 * n + po + sdx)];
        B1[u][3] = 0;
    }

    // ---- Stage 2: MFMA + softmax epilogue per group ----
    #pragma unroll
    for (int u = 0; u < 4; ++u) {
        const int r  = 4 * w + u;
        const int po = (u & 1) ^ 1;

        union { uint u4[4]; half8 v; } b0c = {{B0[u][0], B0[u][1], B0[u][2], B0[u][3]}};
        union { uint u4[4]; half8 v; } b1c = {{B1[u][0], B1[u][1], B1[u][2], B1[u][3]}};

        f32x16 acc = {};
        acc = __builtin_amdgcn_mfma_f32_32x32x16_f16(po ? a0p1 : a0p0, b0c.v, acc, 0, 0, 0);
        acc = __builtin_amdgcn_mfma_f32_32x32x16_f16(po ? a1p1 : a1p0, b1c.v, acc, 0, 0, 0);

        // Channel-duplicated A: even regs = sel, odd regs = green (all 8 pairs).
        float se = 0.f, eg = 0.f;
        #pragma unroll
        for (int rr = 0; rr < 16; rr += 2) {
            float e = __builtin_amdgcn_exp2f(acc[rr] * L2E);
            se += e;
            eg = fmaf(e, acc[rr + 1], eg);
        }
        float gh = eg * __builtin_amdgcn_rcpf(se);

        if (h == 1) {
            // pass-through tap lives in this lane's B0 fragment (row r+2):
            // po=1 -> b0[0] (col 2n+2); po=0 -> b0[3] (col 2n+3)
            float pass = (float)(po ? b0c.v[0] : b0c.v[3]);
            float2 o;
            if (po) { o.x = pass; o.y = gh; }     // y even: (pass, comp)
            else    { o.x = gh;   o.y = pass; }   // y odd:  (comp, pass)
            *(float2*)(outp + (size_t)(by0 + r) * 1024 + bx0 + 2 * n) = o;
        }
    }
}

// ---- fallback (ws too small): self-contained, verified R9-class kernel ----
__global__ __launch_bounds__(256, 2)
void demosaick_fallback(const float* __restrict__ mosaick,
                        const float* __restrict__ sel_filts,
                        const float* __restrict__ green_filts,
                        float* __restrict__ out) {
    __shared__ __align__(16) _Float16 smem[3456];
    const int tid = threadIdx.x;
    const int b   = blockIdx.z;
    const int by0 = blockIdx.y * 16, bx0 = blockIdx.x * 64;
    const float* img = mosaick + (size_t)b * HW_;

    for (int idx = tid; idx < 1360; idx += 256) {
        int row = idx / 68, col = idx - row * 68;
        int gy = by0 - 2 + row; gy = gy < 0 ? 0 : (gy > 1023 ? 1023 : gy);
        int gx = bx0 - 2 + col; gx = gx < 0 ? 0 : (gx > 1023 ? 1023 : gx);
        smem[idx] = (_Float16)img[gy * 1024 + gx];
    }
    for (int idx = tid; idx < 2048; idx += 256) {
        int po = idx >> 10, m = (idx >> 5) & 31, kk = idx & 31;
        int dy, dx;
        tap_from_kk(po, kk, dy, dx);
        float v = 0.f;
        if (dy >= 0) {
            int t = m & 3;
            int p = 2 * ((m >> 2) >> 1) + (t >> 1);
            v = ((t & 1) ? green_filts : sel_filts)[p * 25 + dy * 5 + dx];
        }
        smem[1360 + idx] = (_Float16)v;
    }
    for (int idx = tid; idx < 32; idx += 256) smem[3408 + idx] = (_Float16)0.f;
    __syncthreads();

    const int lane = tid & 63, w = tid >> 6;
    const int n = lane & 31, h = lane >> 5;
    const half8 a0p0 = *(const half8*)&smem[1360 +        n * 32 + h * 8];
    const half8 a1p0 = *(const half8*)&smem[1360 +        n * 32 + 16 + h * 8];
    const half8 a0p1 = *(const half8*)&smem[1360 + 1024 + n * 32 + h * 8];
    const half8 a1p1 = *(const half8*)&smem[1360 + 1024 + n * 32 + 16 + h * 8];

    const uint* smw = (const uint*)smem;
    const unsigned short* sms = (const unsigned short*)smem;
    float* outp = out + (size_t)b * HW_;
    const float L2E = 1.44269504f;

    #pragma unroll
    for (int u = 0; u < 4; ++u) {
        const int r  = 4 * w + u;
        const int po = (u & 1) ^ 1;
        const int pb = po, sdx = po ? 0 : 4;
        const int e0 = (r + 2 * h) * 68 + 2 * n + po;
        const int e4 = (r + 4) * 68 + 2 * n + po;
        const int rs0 = h ? 3 : 0, rs1 = h ? 4 : 1;

        uint B0x = smw[(e0 + pb) >> 1];
        uint B0y = smw[(e0 + pb + 2) >> 1];
        uint B0z = smw[(e0 + 68 + pb) >> 1];
        uint B0w = smw[(e0 + 68 + pb + 2) >> 1];
        uint B1x = smw[(e4 + pb + 2 * h) >> 1];
        uint us0 = sms[(r + rs0) * 68 + 2 * n + po + sdx];
        uint us1 = sms[(r + rs1) * 68 + 2 * n + po + sdx];
        uint B1y = us0 | (us1 << 16);
        uint B1z = sms[h ? 3408 : ((r + 2) * 68 + 2 * n + po + sdx)];
        uint B1w = 0;

        union { uint u4[4]; half8 v; } b0c = {{B0x, B0y, B0z, B0w}};
        union { uint u4[4]; half8 v; } b1c = {{B1x, B1y, B1z, B1w}};

        f32x16 acc = {};
        acc = __builtin_amdgcn_mfma_f32_32x32x16_f16(po ? a0p1 : a0p0, b0c.v, acc, 0, 0, 0);
        acc = __builtin_amdgcn_mfma_f32_32x32x16_f16(po ? a1p1 : a1p0, b1c.v, acc, 0, 0, 0);

        float se = 0.f, eg = 0.f;
        #pragma unroll
        for (int rr = 0; rr < 16; rr += 2) {
            float e = __builtin_amdgcn_exp2f(acc[rr] * L2E);
            se += e;
            eg = fmaf(e, acc[rr + 1], eg);
        }
        float gh = eg * __builtin_amdgcn_rcpf(se);

        if (h == 1) {
            float pass = (float)(po ? b0c.v[0] : b0c.v[3]);
            float2 o;
            if (po) { o.x = pass; o.y = gh; }
            else    { o.x = gh;   o.y = pass; }
            *(float2*)(outp + (size_t)(by0 + r) * 1024 + bx0 + 2 * n) = o;
        }
    }
}

extern "C" void kernel_launch(void* const* d_in, const int* in_sizes, int n_in,
                              void* d_out, int out_size, void* d_ws, size_t ws_size,
                              hipStream_t stream) {
    const float* mosaick     = (const float*)d_in[0];
    const float* sel_filts   = (const float*)d_in[1];
    const float* green_filts = (const float*)d_in[2];
    float* out = (float*)d_out;
    const int B = in_sizes[0] / HW_;          // 8
    dim3 grid(1024 / 64, 1024 / 16, B);       // (16, 64, 8) = 8192 blocks
    dim3 block(256, 1, 1);

    if (ws_size >= 4096) {
        _Float16* tbl = (_Float16*)d_ws;
        hipLaunchKernelGGL(build_filter_table, dim3(8), dim3(256), 0, stream,
                           sel_filts, green_filts, tbl);
        hipLaunchKernelGGL(demosaick_main, grid, block, 0, stream,
                           mosaick, tbl, out);
    } else {
        hipLaunchKernelGGL(demosaick_fallback, grid, block, 0, stream,
                           mosaick, sel_filts, green_filts, out);
    }
}